// Round 8
// baseline (224.149 us; speedup 1.0000x reference)
//
#include <hip/hip_runtime.h>
#include <hip/hip_bf16.h>

#define BB 4
#define TT 2048
#define CC 768
#define HH 12
#define DD 64
#define MM (BB * TT)      // 8192
#define BH (BB * HH)      // 48

typedef __bf16 bf16_t;
typedef __bf16 bf16x8 __attribute__((ext_vector_type(8)));
typedef __bf16 bf16x4 __attribute__((ext_vector_type(4)));
typedef float f32x4 __attribute__((ext_vector_type(4)));

__device__ __forceinline__ float fast_exp2(float x) {
#if __has_builtin(__builtin_amdgcn_exp2f)
    return __builtin_amdgcn_exp2f(x);
#else
    return exp2f(x);
#endif
}

__device__ __forceinline__ uint32_t pk2(float lo, float hi) {
    bf16_t l = (bf16_t)lo, h = (bf16_t)hi;
    uint16_t lu = __builtin_bit_cast(uint16_t, l);
    uint16_t hu = __builtin_bit_cast(uint16_t, h);
    return ((uint32_t)hu << 16) | lu;
}

// async global->LDS, 16B per lane. LDS dest = uniform base + lane*16 (HW rule);
// global address may scatter per-lane (used for the bank-swizzle).
__device__ __forceinline__ void gload_lds16(const void* g, void* l) {
    __builtin_amdgcn_global_load_lds(
        (const __attribute__((address_space(1))) uint32_t*)g,
        (__attribute__((address_space(3))) uint32_t*)l, 16, 0, 0);
}

// ---------------------------------------------------------------- convert f32 -> bf16
__global__ void cvt_f32_bf16(const float* __restrict__ in, bf16_t* __restrict__ out, int n4) {
    int tid = blockIdx.x * blockDim.x + threadIdx.x;
    if (tid >= n4) return;
    float4 v = ((const float4*)in)[tid];
    bf16x4 o;
    o[0] = (bf16_t)v.x; o[1] = (bf16_t)v.y; o[2] = (bf16_t)v.z; o[3] = (bf16_t)v.w;
    ((bf16x4*)out)[tid] = o;
}

// ---------------------------------------------------------------- transpose + convert: W[K][N] f32 -> WT[N][K] bf16
__global__ void transpose_cvt(const float* __restrict__ W, bf16_t* __restrict__ WT, int K, int N) {
    __shared__ bf16_t tile[32][33];
    int k0 = blockIdx.x * 32, n0 = blockIdx.y * 32;
    int tx = threadIdx.x, ty = threadIdx.y;   // block (32, 8)
#pragma unroll
    for (int r = 0; r < 4; ++r) {
        int kl = ty * 4 + r;
        tile[kl][tx] = (bf16_t)W[(size_t)(k0 + kl) * N + n0 + tx];
    }
    __syncthreads();
#pragma unroll
    for (int r = 0; r < 4; ++r) {
        int nl = ty * 4 + r;
        WT[(size_t)(n0 + nl) * K + k0 + tx] = tile[tx][nl];
    }
}

// ================================================================ shared GEMM core
// 1D grid with XCD-friendly swizzle: id -> m = id%8 + 8*(id/(8*NY)), n = (id/8)%NY.
// Each XCD walks one m-tile across all n (A-tile L2-reused NY times); B stays
// L2-resident across m-octaves. 128x128 tile, async global_load_lds staging
// (width 16), double-buffered, single-barrier pipelined K-loop, chunk-rotated.
#define GEMM_CORE(A_, BT_, acc_, NY_)                                                  \
    __shared__ bf16_t As[2][128 * 32];                                                 \
    __shared__ bf16_t Bs[2][128 * 32];                                                 \
    int tid = threadIdx.x;                                                             \
    int wv = tid >> 6, lane = tid & 63, c = lane & 15, quad = lane >> 4;               \
    int wm = (wv >> 1) * 64, wn = (wv & 1) * 64;                                       \
    int bid = blockIdx.x;                                                              \
    int m0 = ((bid & 7) + 8 * (bid / (8 * NY_))) * 128;                                \
    int n0 = ((bid >> 3) % NY_) * 128;                                                 \
    int srow = wv * 32 + (lane >> 2);                                                  \
    int slot = lane & 3;                                                               \
    auto stage = [&](int buf, int k0) {                                                \
        _Pragma("unroll")                                                              \
        for (int ins = 0; ins < 2; ++ins) {                                            \
            int r = srow + ins * 16;                                                   \
            int g = (slot - ((r >> 1) & 3)) & 3;                                       \
            const bf16_t* ga = A_ + (size_t)(m0 + r) * K + k0 + g * 8;                 \
            const bf16_t* gb = BT_ + (size_t)(n0 + r) * K + k0 + g * 8;                \
            gload_lds16(ga, &As[buf][(wv * 32 + ins * 16) * 32]);                      \
            gload_lds16(gb, &Bs[buf][(wv * 32 + ins * 16) * 32]);                      \
        }                                                                              \
    };                                                                                 \
    int s_rd = (quad + ((c >> 1) & 3)) & 3;                                            \
    const int nk = K / 32;                                                             \
    stage(0, 0);                                                                       \
    for (int kt = 0; kt < nk; ++kt) {                                                  \
        __syncthreads();                                                               \
        if (kt + 1 < nk) stage((kt + 1) & 1, (kt + 1) * 32);                           \
        int buf = kt & 1;                                                              \
        bf16x8 af[4], bfr[4];                                                          \
        _Pragma("unroll")                                                              \
        for (int i = 0; i < 4; ++i) af[i] = *(const bf16x8*)&As[buf][(wm + i * 16 + c) * 32 + s_rd * 8];  \
        _Pragma("unroll")                                                              \
        for (int j = 0; j < 4; ++j) bfr[j] = *(const bf16x8*)&Bs[buf][(wn + j * 16 + c) * 32 + s_rd * 8]; \
        _Pragma("unroll")                                                              \
        for (int i = 0; i < 4; ++i)                                                    \
            _Pragma("unroll")                                                          \
            for (int j = 0; j < 4; ++j)                                                \
                acc_[i][j] = __builtin_amdgcn_mfma_f32_16x16x32_bf16(af[i], bfr[j], acc_[i][j], 0, 0, 0); \
    }

// ---------------------------------------------------------------- qkv GEMM, fused bias+rotary+head-split+V-transpose
// Epilogue routes through LDS so every global store is a full-line coalesced
// write (R6 lesson: scattered partial-line stores -> 45x write amplification).
__global__ __launch_bounds__(256, 3) void gemm_qkv(
        const bf16_t* __restrict__ A, const bf16_t* __restrict__ BT,
        const float* __restrict__ bias,
        bf16_t* __restrict__ Qh, bf16_t* __restrict__ Kh, bf16_t* __restrict__ Vt) {
    const int K = 768;
    const int NY = 18;
    __shared__ __align__(16) bf16_t smem[17408];   // stage 32KB, epi 4x(64x68)
    bf16_t* Asp = smem;           // [2][4096]
    bf16_t* Bsp = smem + 8192;    // [2][4096]
    int tid = threadIdx.x;
    int wv = tid >> 6, lane = tid & 63, c = lane & 15, quad = lane >> 4;
    int wm = (wv >> 1) * 64, wn = (wv & 1) * 64;
    int bid = blockIdx.x;
    int m0 = ((bid & 7) + 8 * (bid / (8 * NY))) * 128;
    int n0 = ((bid >> 3) % NY) * 128;
    int srow = wv * 32 + (lane >> 2);
    int slot = lane & 3;
    auto stage = [&](int buf, int k0) {
#pragma unroll
        for (int ins = 0; ins < 2; ++ins) {
            int r = srow + ins * 16;
            int g = (slot - ((r >> 1) & 3)) & 3;
            gload_lds16(A + (size_t)(m0 + r) * K + k0 + g * 8, &Asp[buf * 4096 + (wv * 32 + ins * 16) * 32]);
            gload_lds16(BT + (size_t)(n0 + r) * K + k0 + g * 8, &Bsp[buf * 4096 + (wv * 32 + ins * 16) * 32]);
        }
    };
    int s_rd = (quad + ((c >> 1) & 3)) & 3;
    f32x4 acc[4][4] = {};
    const int nk = K / 32;
    stage(0, 0);
    for (int kt = 0; kt < nk; ++kt) {
        __syncthreads();
        if (kt + 1 < nk) stage((kt + 1) & 1, (kt + 1) * 32);
        int buf = kt & 1;
        bf16x8 af[4], bfr[4];
#pragma unroll
        for (int i = 0; i < 4; ++i) af[i] = *(const bf16x8*)&Asp[buf * 4096 + (wm + i * 16 + c) * 32 + s_rd * 8];
#pragma unroll
        for (int j = 0; j < 4; ++j) bfr[j] = *(const bf16x8*)&Bsp[buf * 4096 + (wn + j * 16 + c) * 32 + s_rd * 8];
#pragma unroll
        for (int i = 0; i < 4; ++i)
#pragma unroll
            for (int j = 0; j < 4; ++j)
                acc[i][j] = __builtin_amdgcn_mfma_f32_16x16x32_bf16(af[i], bfr[j], acc[i][j], 0, 0, 0);
    }
    __syncthreads();                        // all frag reads done; LDS now epilogue staging

    int type = n0 / 768;                    // 0=Q 1=K 2=V (block-uniform)
    int hloc = ((n0 % 768) + wn) >> 6;      // wave's 64 cols = one head
    int bidx = m0 >> 11;
    int colb = n0 + wn;
    int tb = (m0 + wm) & (TT - 1);          // wave's 64-row t-base (mult of 64)
    bf16_t* epi = smem + wv * 4352;         // 64 rows x 68 (+4 pad breaks bank stride)
    int rrow = lane >> 3, cchunk = lane & 7;

    if (type < 2) {
        const float rscale = (type == 0) ? 0.125f * 1.44269504088896f : 1.0f;
#pragma unroll
        for (int j = 0; j < 2; ++j) {
            int dlo = j * 16 + c;
            float infr = fast_exp2(-(float)dlo * 0.4152410118609828f);  // 10000^(-dlo/32)
            float blo = bias[colb + j * 16 + c];
            float bhi = bias[colb + (j + 2) * 16 + c];
#pragma unroll
            for (int i = 0; i < 4; ++i)
#pragma unroll
                for (int r = 0; r < 4; ++r) {
                    int lr = i * 16 + quad * 4 + r;
                    float a = acc[i][j][r] + blo;
                    float b2 = acc[i][j + 2][r] + bhi;
                    float fr = (float)(tb + lr) * infr;
                    float cs, sn;
                    __sincosf(fr, &sn, &cs);
                    epi[lr * 68 + dlo]      = (bf16_t)((a * cs + b2 * sn) * rscale);
                    epi[lr * 68 + dlo + 32] = (bf16_t)((-a * sn + b2 * cs) * rscale);
                }
        }
        bf16_t* dst = (type == 0 ? Qh : Kh) + (size_t)(bidx * HH + hloc) * TT * DD + (size_t)tb * DD;
#pragma unroll
        for (int it = 0; it < 8; ++it) {
            int row = it * 8 + rrow;
            bf16x8 v = *(const bf16x8*)&epi[row * 68 + cchunk * 8];
            *(bf16x8*)&dst[row * 64 + cchunk * 8] = v;    // 1KB/instr, full lines
        }
    } else {
        int kt64 = tb >> 6;
#pragma unroll
        for (int j = 0; j < 4; ++j) {
            int dim = j * 16 + c;
            float bv = bias[colb + j * 16 + c];
            int rot = (dim & 7) * 8;
#pragma unroll
            for (int i = 0; i < 4; ++i)
#pragma unroll
                for (int r = 0; r < 4; ++r) {
                    int tin = i * 16 + quad * 4 + r;
                    epi[dim * 68 + ((tin + rot) & 63)] = (bf16_t)(acc[i][j][r] + bv);
                }
        }
        bf16_t* dstV = Vt + (size_t)(bidx * HH + hloc) * (TT / 64) * 4096 + (size_t)kt64 * 4096;
#pragma unroll
        for (int it = 0; it < 8; ++it) {
            int dim = it * 8 + rrow;
            int src = ((cchunk + (dim & 7)) & 7) * 8;     // un-rotate
            bf16x8 v = *(const bf16x8*)&epi[dim * 68 + src];
            *(bf16x8*)&dstV[dim * 64 + cchunk * 8] = v;   // 1KB/instr, full lines
        }
    }
}

// ---------------------------------------------------------------- proj GEMM: out f32 = Yb @ WpT^T + bias
__global__ __launch_bounds__(256, 3) void gemm_proj(
        const bf16_t* __restrict__ A, const bf16_t* __restrict__ BT,
        const float* __restrict__ bias, float* __restrict__ Cout) {
    const int K = 768;
    f32x4 acc[4][4] = {};
    GEMM_CORE(A, BT, acc, 6)
#pragma unroll
    for (int j = 0; j < 4; ++j) {
        int col = n0 + wn + j * 16 + c;
        float bv = bias[col];
#pragma unroll
        for (int i = 0; i < 4; ++i) {
            int row = m0 + wm + i * 16 + quad * 4;
#pragma unroll
            for (int r = 0; r < 4; ++r)
                Cout[(size_t)(row + r) * CC + col] = acc[i][j][r] + bv;
        }
    }
}

// ---------------------------------------------------------------- flash attention v2: balanced strip-pairs
// 768 blocks x 2 waves (128 thr). Block = (bh, pair a): processes 64-query
// tile (31-a) then tile a sequentially -> every block costs exactly 33
// 64-key tiles (uniform durations; R7's 2..32 spread caused the occupancy
// decay). bh XCD-pinned (blk&7) so K/V (3MB/XCD) stay L2-local. Per-wave
// math identical to the R5-verified kernel.
__global__ __launch_bounds__(128, 2) void flash_attn(
        const bf16_t* __restrict__ Q, const bf16_t* __restrict__ Kc,
        const bf16_t* __restrict__ Vt, bf16_t* __restrict__ Y) {
    __shared__ bf16_t Ks[2][64 * 64];
    __shared__ bf16_t Vs[2][64 * 64];
    int blk = blockIdx.x;
    int xcd = blk & 7;
    int rest = blk >> 3;               // 0..95
    int bh = xcd * 6 + rest % 6;
    int a = rest / 6;                  // 0..15
    int wv = threadIdx.x >> 6, lane = threadIdx.x & 63;
    int b = bh / HH, h = bh - b * HH;
    int c = lane & 15, quad = lane >> 4;
    const bf16_t* Kg = Kc + (size_t)bh * TT * DD;
    const bf16_t* Vg = Vt + (size_t)bh * (TT / 64) * 4096;

    int srow8 = lane >> 3;             // stage: 8 lanes/row
    int slot = lane & 7;
    auto stage = [&](int buf, int kt64) {
#pragma unroll
        for (int ins = 0; ins < 4; ++ins) {
            int r = wv * 32 + ins * 8 + srow8;
            int g = (slot - (r & 7)) & 7;
            gload_lds16(Kg + (size_t)(kt64 * 64 + r) * 64 + g * 8, &Ks[buf][(wv * 32 + ins * 8) * 64]);
            gload_lds16(Vg + (size_t)kt64 * 4096 + r * 64 + g * 8, &Vs[buf][(wv * 32 + ins * 8) * 64]);
        }
    };

    int lane_lo = c + ((quad & 1) << 5);
    int lane_hi = lane_lo + 16;
    bool lowq = (quad < 2);

#pragma unroll
    for (int ph = 0; ph < 2; ++ph) {
        int tq = (ph == 0) ? (31 - a) : a;     // heavy phase first
        int qbw = tq * 64 + wv * 32;
        const bf16_t* Qg = Q + ((size_t)bh * TT + qbw) * DD;

        bf16x8 qf[2][2];
#pragma unroll
        for (int s = 0; s < 2; ++s)
#pragma unroll
            for (int ch = 0; ch < 2; ++ch)
                qf[s][ch] = *(const bf16x8*)(Qg + (s * 16 + c) * DD + ch * 32 + quad * 8);

        f32x4 O[2][4] = {};          // O^T: col=query=c, row=d=nt*16+quad*4+r
        float lsum[2] = {0.0f, 0.0f};

        int ntiles = tq + 1;
        stage(0, 0);
        for (int kt = 0; kt < ntiles; ++kt) {
            __syncthreads();                         // drains stage(kt); buffer-reuse sync
            if (kt + 1 < ntiles) stage((kt + 1) & 1, kt + 1);
            int buf = kt & 1;
#pragma unroll
            for (int t32 = 0; t32 < 2; ++t32) {
                int ks = kt * 64 + t32 * 32;
                if (ks > qbw) continue;              // beyond this wave's causal range
                bool masked = (ks == qbw);
                bf16x8 kf[2][2], vf[4];
#pragma unroll
                for (int t2 = 0; t2 < 2; ++t2)
#pragma unroll
                    for (int ch = 0; ch < 2; ++ch) {
                        int row = t32 * 32 + t2 * 16 + c;
                        int sl = (ch * 4 + quad + (c & 7)) & 7;
                        kf[t2][ch] = *(const bf16x8*)&Ks[buf][row * 64 + sl * 8];
                    }
#pragma unroll
                for (int nt = 0; nt < 4; ++nt) {
                    int row = nt * 16 + c;
                    int sl = (t32 * 4 + quad + (c & 7)) & 7;
                    vf[nt] = *(const bf16x8*)&Vs[buf][row * 64 + sl * 8];
                }
                f32x4 st[2][2] = {};
#pragma unroll
                for (int s = 0; s < 2; ++s)
#pragma unroll
                    for (int t2 = 0; t2 < 2; ++t2) {
                        st[s][t2] = __builtin_amdgcn_mfma_f32_16x16x32_bf16(kf[t2][0], qf[s][0], st[s][t2], 0, 0, 0);
                        st[s][t2] = __builtin_amdgcn_mfma_f32_16x16x32_bf16(kf[t2][1], qf[s][1], st[s][t2], 0, 0, 0);
                    }
#pragma unroll
                for (int s = 0; s < 2; ++s) {
                    float pv[2][4];
#pragma unroll
                    for (int t2 = 0; t2 < 2; ++t2)
#pragma unroll
                        for (int r = 0; r < 4; ++r) {
                            float p = fast_exp2(st[s][t2][r]);
                            if (masked) {
                                int keyl = t2 * 16 + quad * 4 + r;
                                if (keyl > s * 16 + c) p = 0.0f;
                            }
                            pv[t2][r] = p;
                        }
                    lsum[s] += ((pv[0][0] + pv[0][1]) + (pv[0][2] + pv[0][3]))
                             + ((pv[1][0] + pv[1][1]) + (pv[1][2] + pv[1][3]));
                    uint32_t pk0a = pk2(pv[0][0], pv[0][1]), pk0b = pk2(pv[0][2], pv[0][3]);
                    uint32_t pk1a = pk2(pv[1][0], pv[1][1]), pk1b = pk2(pv[1][2], pv[1][3]);
                    union { uint32_t u[4]; bf16x8 v; } pf;
                    {
                        uint32_t x0 = (uint32_t)__shfl((int)pk0a, lane_lo);
                        uint32_t y0 = (uint32_t)__shfl((int)pk1a, lane_lo);
                        pf.u[0] = lowq ? x0 : y0;
                        uint32_t x1 = (uint32_t)__shfl((int)pk0b, lane_lo);
                        uint32_t y1 = (uint32_t)__shfl((int)pk1b, lane_lo);
                        pf.u[1] = lowq ? x1 : y1;
                        uint32_t x2 = (uint32_t)__shfl((int)pk0a, lane_hi);
                        uint32_t y2 = (uint32_t)__shfl((int)pk1a, lane_hi);
                        pf.u[2] = lowq ? x2 : y2;
                        uint32_t x3 = (uint32_t)__shfl((int)pk0b, lane_hi);
                        uint32_t y3 = (uint32_t)__shfl((int)pk1b, lane_hi);
                        pf.u[3] = lowq ? x3 : y3;
                    }
#pragma unroll
                    for (int nt = 0; nt < 4; ++nt)
                        O[s][nt] = __builtin_amdgcn_mfma_f32_16x16x32_bf16(vf[nt], pf.v, O[s][nt], 0, 0, 0);
                }
            }
        }

#pragma unroll
        for (int s = 0; s < 2; ++s) {
            float l = lsum[s];
            l += __shfl_xor(l, 16);
            l += __shfl_xor(l, 32);
            float inv_l = 1.0f / l;
            int row = b * TT + qbw + s * 16 + c;
#pragma unroll
            for (int nt = 0; nt < 4; ++nt) {
                bf16x4 ov;
#pragma unroll
                for (int r = 0; r < 4; ++r) ov[r] = (bf16_t)(O[s][nt][r] * inv_l);
                *(bf16x4*)(Y + (size_t)row * CC + h * DD + nt * 16 + quad * 4) = ov;
            }
        }
        __syncthreads();   // phase 2's stage(0,0) must not overwrite live buf
    }
}

// ---------------------------------------------------------------- launch
extern "C" void kernel_launch(void* const* d_in, const int* in_sizes, int n_in,
                              void* d_out, int out_size, void* d_ws, size_t ws_size,
                              hipStream_t stream) {
    const float* x      = (const float*)d_in[0];
    const float* W_attn = (const float*)d_in[1];
    const float* b_attn = (const float*)d_in[2];
    const float* W_proj = (const float*)d_in[3];
    const float* b_proj = (const float*)d_in[4];
    float* out = (float*)d_out;

    unsigned char* ws = (unsigned char*)d_ws;
    size_t off = 0;
    auto alloc = [&](size_t bytes) { void* p = ws + off; off += (bytes + 255) & ~(size_t)255; return p; };
    bf16_t* xb  = (bf16_t*)alloc((size_t)MM * CC * 2);
    bf16_t* WaT = (bf16_t*)alloc((size_t)3 * CC * CC * 2);
    bf16_t* WpT = (bf16_t*)alloc((size_t)CC * CC * 2);
    bf16_t* Qh  = (bf16_t*)alloc((size_t)BH * TT * DD * 2);
    bf16_t* Kh  = (bf16_t*)alloc((size_t)BH * TT * DD * 2);
    bf16_t* Vt  = (bf16_t*)alloc((size_t)BH * TT * DD * 2);
    bf16_t* Yb  = (bf16_t*)alloc((size_t)MM * CC * 2);

    cvt_f32_bf16<<<(MM * CC / 4 + 255) / 256, 256, 0, stream>>>(x, xb, MM * CC / 4);
    transpose_cvt<<<dim3(CC / 32, 3 * CC / 32), dim3(32, 8), 0, stream>>>(W_attn, WaT, CC, 3 * CC);
    transpose_cvt<<<dim3(CC / 32, CC / 32), dim3(32, 8), 0, stream>>>(W_proj, WpT, CC, CC);
    gemm_qkv<<<dim3(64 * 18), 256, 0, stream>>>(xb, WaT, b_attn, Qh, Kh, Vt);
    flash_attn<<<dim3(768), 128, 0, stream>>>(Qh, Kh, Vt, Yb);
    gemm_proj<<<dim3(64 * 6), 256, 0, stream>>>(Yb, WpT, b_proj, out);
}

// Round 9
// 199.309 us; speedup vs baseline: 1.1246x; 1.1246x over previous
//
#include <hip/hip_runtime.h>
#include <hip/hip_bf16.h>

#define BB 4
#define TT 2048
#define CC 768
#define HH 12
#define DD 64
#define MM (BB * TT)      // 8192
#define BH (BB * HH)      // 48

typedef __bf16 bf16_t;
typedef __bf16 bf16x8 __attribute__((ext_vector_type(8)));
typedef __bf16 bf16x4 __attribute__((ext_vector_type(4)));
typedef float f32x4 __attribute__((ext_vector_type(4)));

__device__ __forceinline__ float fast_exp2(float x) {
#if __has_builtin(__builtin_amdgcn_exp2f)
    return __builtin_amdgcn_exp2f(x);
#else
    return exp2f(x);
#endif
}

__device__ __forceinline__ uint32_t pk2(float lo, float hi) {
    bf16_t l = (bf16_t)lo, h = (bf16_t)hi;
    uint16_t lu = __builtin_bit_cast(uint16_t, l);
    uint16_t hu = __builtin_bit_cast(uint16_t, h);
    return ((uint32_t)hu << 16) | lu;
}

// async global->LDS, 16B per lane. LDS dest = uniform base + lane*16 (HW rule);
// global address may scatter per-lane (used for the bank-swizzle).
__device__ __forceinline__ void gload_lds16(const void* g, void* l) {
    __builtin_amdgcn_global_load_lds(
        (const __attribute__((address_space(1))) uint32_t*)g,
        (__attribute__((address_space(3))) uint32_t*)l, 16, 0, 0);
}

// ---------------------------------------------------------------- convert f32 -> bf16
__global__ void cvt_f32_bf16(const float* __restrict__ in, bf16_t* __restrict__ out, int n4) {
    int tid = blockIdx.x * blockDim.x + threadIdx.x;
    if (tid >= n4) return;
    float4 v = ((const float4*)in)[tid];
    bf16x4 o;
    o[0] = (bf16_t)v.x; o[1] = (bf16_t)v.y; o[2] = (bf16_t)v.z; o[3] = (bf16_t)v.w;
    ((bf16x4*)out)[tid] = o;
}

// ---------------------------------------------------------------- transpose + convert: W[K][N] f32 -> WT[N][K] bf16
__global__ void transpose_cvt(const float* __restrict__ W, bf16_t* __restrict__ WT, int K, int N) {
    __shared__ bf16_t tile[32][33];
    int k0 = blockIdx.x * 32, n0 = blockIdx.y * 32;
    int tx = threadIdx.x, ty = threadIdx.y;   // block (32, 8)
#pragma unroll
    for (int r = 0; r < 4; ++r) {
        int kl = ty * 4 + r;
        tile[kl][tx] = (bf16_t)W[(size_t)(k0 + kl) * N + n0 + tx];
    }
    __syncthreads();
#pragma unroll
    for (int r = 0; r < 4; ++r) {
        int nl = ty * 4 + r;
        WT[(size_t)(n0 + nl) * K + k0 + tx] = tile[tx][nl];
    }
}

// ================================================================ shared GEMM core (R7-verified)
#define GEMM_CORE(A_, BT_, acc_)                                                       \
    __shared__ bf16_t As[2][128 * 32];                                                 \
    __shared__ bf16_t Bs[2][128 * 32];                                                 \
    int tid = threadIdx.x;                                                             \
    int wv = tid >> 6, lane = tid & 63, c = lane & 15, quad = lane >> 4;               \
    int wm = (wv >> 1) * 64, wn = (wv & 1) * 64;                                       \
    int m0 = blockIdx.x * 128, n0 = blockIdx.y * 128;                                  \
    int srow = wv * 32 + (lane >> 2);                                                  \
    int slot = lane & 3;                                                               \
    auto stage = [&](int buf, int k0) {                                                \
        _Pragma("unroll")                                                              \
        for (int ins = 0; ins < 2; ++ins) {                                            \
            int r = srow + ins * 16;                                                   \
            int g = (slot - ((r >> 1) & 3)) & 3;                                       \
            const bf16_t* ga = A_ + (size_t)(m0 + r) * K + k0 + g * 8;                 \
            const bf16_t* gb = BT_ + (size_t)(n0 + r) * K + k0 + g * 8;                \
            gload_lds16(ga, &As[buf][(wv * 32 + ins * 16) * 32]);                      \
            gload_lds16(gb, &Bs[buf][(wv * 32 + ins * 16) * 32]);                      \
        }                                                                              \
    };                                                                                 \
    int s_rd = (quad + ((c >> 1) & 3)) & 3;                                            \
    const int nk = K / 32;                                                             \
    stage(0, 0);                                                                       \
    for (int kt = 0; kt < nk; ++kt) {                                                  \
        __syncthreads();                                                               \
        if (kt + 1 < nk) stage((kt + 1) & 1, (kt + 1) * 32);                           \
        int buf = kt & 1;                                                              \
        bf16x8 af[4], bfr[4];                                                          \
        _Pragma("unroll")                                                              \
        for (int i = 0; i < 4; ++i) af[i] = *(const bf16x8*)&As[buf][(wm + i * 16 + c) * 32 + s_rd * 8];  \
        _Pragma("unroll")                                                              \
        for (int j = 0; j < 4; ++j) bfr[j] = *(const bf16x8*)&Bs[buf][(wn + j * 16 + c) * 32 + s_rd * 8]; \
        _Pragma("unroll")                                                              \
        for (int i = 0; i < 4; ++i)                                                    \
            _Pragma("unroll")                                                          \
            for (int j = 0; j < 4; ++j)                                                \
                acc_[i][j] = __builtin_amdgcn_mfma_f32_16x16x32_bf16(af[i], bfr[j], acc_[i][j], 0, 0, 0); \
    }

// ---------------------------------------------------------------- qkv GEMM, fused bias+rotary+head-split+V-transpose
// Epilogue routes through LDS so every global store is a full-line coalesced
// write (R6 lesson: scattered partial-line stores -> 45x write amplification).
__global__ __launch_bounds__(256, 3) void gemm_qkv(
        const bf16_t* __restrict__ A, const bf16_t* __restrict__ BT,
        const float* __restrict__ bias,
        bf16_t* __restrict__ Qh, bf16_t* __restrict__ Kh, bf16_t* __restrict__ Vt) {
    const int K = 768;
    __shared__ __align__(16) bf16_t smem[17408];   // stage 32KB, epi 4x(64x68)
    bf16_t* Asp = smem;           // [2][4096]
    bf16_t* Bsp = smem + 8192;    // [2][4096]
    int tid = threadIdx.x;
    int wv = tid >> 6, lane = tid & 63, c = lane & 15, quad = lane >> 4;
    int wm = (wv >> 1) * 64, wn = (wv & 1) * 64;
    int m0 = blockIdx.x * 128, n0 = blockIdx.y * 128;
    int srow = wv * 32 + (lane >> 2);
    int slot = lane & 3;
    auto stage = [&](int buf, int k0) {
#pragma unroll
        for (int ins = 0; ins < 2; ++ins) {
            int r = srow + ins * 16;
            int g = (slot - ((r >> 1) & 3)) & 3;
            gload_lds16(A + (size_t)(m0 + r) * K + k0 + g * 8, &Asp[buf * 4096 + (wv * 32 + ins * 16) * 32]);
            gload_lds16(BT + (size_t)(n0 + r) * K + k0 + g * 8, &Bsp[buf * 4096 + (wv * 32 + ins * 16) * 32]);
        }
    };
    int s_rd = (quad + ((c >> 1) & 3)) & 3;
    f32x4 acc[4][4] = {};
    const int nk = K / 32;
    stage(0, 0);
    for (int kt = 0; kt < nk; ++kt) {
        __syncthreads();
        if (kt + 1 < nk) stage((kt + 1) & 1, (kt + 1) * 32);
        int buf = kt & 1;
        bf16x8 af[4], bfr[4];
#pragma unroll
        for (int i = 0; i < 4; ++i) af[i] = *(const bf16x8*)&Asp[buf * 4096 + (wm + i * 16 + c) * 32 + s_rd * 8];
#pragma unroll
        for (int j = 0; j < 4; ++j) bfr[j] = *(const bf16x8*)&Bsp[buf * 4096 + (wn + j * 16 + c) * 32 + s_rd * 8];
#pragma unroll
        for (int i = 0; i < 4; ++i)
#pragma unroll
            for (int j = 0; j < 4; ++j)
                acc[i][j] = __builtin_amdgcn_mfma_f32_16x16x32_bf16(af[i], bfr[j], acc[i][j], 0, 0, 0);
    }
    __syncthreads();                        // all frag reads done; LDS now epilogue staging

    int type = n0 / 768;                    // 0=Q 1=K 2=V (block-uniform)
    int hloc = ((n0 % 768) + wn) >> 6;      // wave's 64 cols = one head
    int bidx = m0 >> 11;
    int colb = n0 + wn;
    int tb = (m0 + wm) & (TT - 1);          // wave's 64-row t-base (mult of 64)
    bf16_t* epi = smem + wv * 4352;         // 64 rows x 68 (+4 pad breaks bank stride)
    int rrow = lane >> 3, cchunk = lane & 7;

    if (type < 2) {
        const float rscale = (type == 0) ? 0.125f * 1.44269504088896f : 1.0f;
#pragma unroll
        for (int j = 0; j < 2; ++j) {
            int dlo = j * 16 + c;
            float infr = fast_exp2(-(float)dlo * 0.4152410118609828f);  // 10000^(-dlo/32)
            float blo = bias[colb + j * 16 + c];
            float bhi = bias[colb + (j + 2) * 16 + c];
#pragma unroll
            for (int i = 0; i < 4; ++i)
#pragma unroll
                for (int r = 0; r < 4; ++r) {
                    int lr = i * 16 + quad * 4 + r;
                    float a = acc[i][j][r] + blo;
                    float b2 = acc[i][j + 2][r] + bhi;
                    float fr = (float)(tb + lr) * infr;
                    float cs, sn;
                    __sincosf(fr, &sn, &cs);
                    epi[lr * 68 + dlo]      = (bf16_t)((a * cs + b2 * sn) * rscale);
                    epi[lr * 68 + dlo + 32] = (bf16_t)((-a * sn + b2 * cs) * rscale);
                }
        }
        bf16_t* dst = (type == 0 ? Qh : Kh) + (size_t)(bidx * HH + hloc) * TT * DD + (size_t)tb * DD;
#pragma unroll
        for (int it = 0; it < 8; ++it) {
            int row = it * 8 + rrow;
            bf16x8 v = *(const bf16x8*)&epi[row * 68 + cchunk * 8];
            *(bf16x8*)&dst[row * 64 + cchunk * 8] = v;    // 1KB/instr, full lines
        }
    } else {
        int kt64 = tb >> 6;
#pragma unroll
        for (int j = 0; j < 4; ++j) {
            int dim = j * 16 + c;
            float bv = bias[colb + j * 16 + c];
            int rot = (dim & 7) * 8;
#pragma unroll
            for (int i = 0; i < 4; ++i)
#pragma unroll
                for (int r = 0; r < 4; ++r) {
                    int tin = i * 16 + quad * 4 + r;
                    epi[dim * 68 + ((tin + rot) & 63)] = (bf16_t)(acc[i][j][r] + bv);
                }
        }
        bf16_t* dstV = Vt + (size_t)(bidx * HH + hloc) * (TT / 64) * 4096 + (size_t)kt64 * 4096;
#pragma unroll
        for (int it = 0; it < 8; ++it) {
            int dim = it * 8 + rrow;
            int src = ((cchunk + (dim & 7)) & 7) * 8;     // un-rotate
            bf16x8 v = *(const bf16x8*)&epi[dim * 68 + src];
            *(bf16x8*)&dstV[dim * 64 + cchunk * 8] = v;   // 1KB/instr, full lines
        }
    }
}

// ---------------------------------------------------------------- proj GEMM: out f32 = Yb @ WpT^T + bias
__global__ __launch_bounds__(256, 3) void gemm_proj(
        const bf16_t* __restrict__ A, const bf16_t* __restrict__ BT,
        const float* __restrict__ bias, float* __restrict__ Cout) {
    const int K = 768;
    f32x4 acc[4][4] = {};
    GEMM_CORE(A, BT, acc)
#pragma unroll
    for (int j = 0; j < 4; ++j) {
        int col = n0 + wn + j * 16 + c;
        float bv = bias[col];
#pragma unroll
        for (int i = 0; i < 4; ++i) {
            int row = m0 + wm + i * 16 + quad * 4;
#pragma unroll
            for (int r = 0; r < 4; ++r)
                Cout[(size_t)(row + r) * CC + col] = acc[i][j][r] + bv;
        }
    }
}

// ---------------------------------------------------------------- flash attention, LDS-staged block-cooperative (R5/R7-verified math)
// 768 blocks x 4 waves; block = 128 queries of one head. CU-balanced rank
// remap: assuming ~round-robin blk->CU dispatch, each CU's 3 resident blocks
// get a {heavy, light, middle} work triple (sum ~const) so occupancy stays
// ~12 waves/CU to the end instead of decaying (R7's blocks spread 2..32
// key-tiles; R8 showed cutting waves for balance loses -- this keeps both).
__global__ __launch_bounds__(256, 3) void flash_attn(
        const bf16_t* __restrict__ Q, const bf16_t* __restrict__ Kc,
        const bf16_t* __restrict__ Vt, bf16_t* __restrict__ Y) {
    __shared__ bf16_t Ks[2][64 * 64];
    __shared__ bf16_t Vs[2][64 * 64];
    int blk = blockIdx.x;
    // rank 0..767 sorted heavy-first; blk<256 heavy, [256,512) lightest, rest middle
    int r0 = (blk < 256) ? blk : ((blk < 512) ? (1023 - blk) : (blk - 256));
    int qt = 15 - (r0 / 48);
    int bh = r0 % 48;
    int wv = threadIdx.x >> 6, lane = threadIdx.x & 63;
    int b = bh / HH, h = bh - b * HH;
    int c = lane & 15, quad = lane >> 4;
    int qbw = qt * 128 + wv * 32;
    const bf16_t* Qg = Q + ((size_t)bh * TT + qbw) * DD;
    const bf16_t* Kg = Kc + (size_t)bh * TT * DD;
    const bf16_t* Vg = Vt + (size_t)bh * (TT / 64) * 4096;

    bf16x8 qf[2][2];
#pragma unroll
    for (int s = 0; s < 2; ++s)
#pragma unroll
        for (int ch = 0; ch < 2; ++ch)
            qf[s][ch] = *(const bf16x8*)(Qg + (s * 16 + c) * DD + ch * 32 + quad * 8);

    int srow = wv * 16 + (lane >> 3);
    int slot = lane & 7;
    auto stage = [&](int buf, int kt64) {
#pragma unroll
        for (int ins = 0; ins < 2; ++ins) {
            int r = srow + ins * 8;
            int g = (slot - (r & 7)) & 7;
            gload_lds16(Kg + (size_t)(kt64 * 64 + r) * 64 + g * 8, &Ks[buf][(wv * 16 + ins * 8) * 64]);
            gload_lds16(Vg + (size_t)kt64 * 4096 + r * 64 + g * 8, &Vs[buf][(wv * 16 + ins * 8) * 64]);
        }
    };

    f32x4 O[2][4] = {};          // O^T: col=query=c, row=d=nt*16+quad*4+r
    float lsum[2] = {0.0f, 0.0f};
    int lane_lo = c + ((quad & 1) << 5);
    int lane_hi = lane_lo + 16;
    bool lowq = (quad < 2);

    int ntiles = 2 * qt + 2;
    stage(0, 0);
    for (int kt = 0; kt < ntiles; ++kt) {
        __syncthreads();                         // drains stage(kt); buffer-reuse sync
        if (kt + 1 < ntiles) stage((kt + 1) & 1, kt + 1);
        int buf = kt & 1;
#pragma unroll
        for (int t32 = 0; t32 < 2; ++t32) {
            int ks = kt * 64 + t32 * 32;
            if (ks > qbw) continue;              // beyond this wave's causal range
            bool masked = (ks == qbw);
            bf16x8 kf[2][2], vf[4];
#pragma unroll
            for (int t2 = 0; t2 < 2; ++t2)
#pragma unroll
                for (int ch = 0; ch < 2; ++ch) {
                    int row = t32 * 32 + t2 * 16 + c;
                    int sl = (ch * 4 + quad + (c & 7)) & 7;
                    kf[t2][ch] = *(const bf16x8*)&Ks[buf][row * 64 + sl * 8];
                }
#pragma unroll
            for (int nt = 0; nt < 4; ++nt) {
                int row = nt * 16 + c;
                int sl = (t32 * 4 + quad + (c & 7)) & 7;
                vf[nt] = *(const bf16x8*)&Vs[buf][row * 64 + sl * 8];
            }
            f32x4 st[2][2] = {};
#pragma unroll
            for (int s = 0; s < 2; ++s)
#pragma unroll
                for (int t2 = 0; t2 < 2; ++t2) {
                    st[s][t2] = __builtin_amdgcn_mfma_f32_16x16x32_bf16(kf[t2][0], qf[s][0], st[s][t2], 0, 0, 0);
                    st[s][t2] = __builtin_amdgcn_mfma_f32_16x16x32_bf16(kf[t2][1], qf[s][1], st[s][t2], 0, 0, 0);
                }
#pragma unroll
            for (int s = 0; s < 2; ++s) {
                float pv[2][4];
#pragma unroll
                for (int t2 = 0; t2 < 2; ++t2)
#pragma unroll
                    for (int r = 0; r < 4; ++r) {
                        float p = fast_exp2(st[s][t2][r]);
                        if (masked) {
                            int keyl = t2 * 16 + quad * 4 + r;
                            if (keyl > s * 16 + c) p = 0.0f;
                        }
                        pv[t2][r] = p;
                    }
                lsum[s] += ((pv[0][0] + pv[0][1]) + (pv[0][2] + pv[0][3]))
                         + ((pv[1][0] + pv[1][1]) + (pv[1][2] + pv[1][3]));
                uint32_t pk0a = pk2(pv[0][0], pv[0][1]), pk0b = pk2(pv[0][2], pv[0][3]);
                uint32_t pk1a = pk2(pv[1][0], pv[1][1]), pk1b = pk2(pv[1][2], pv[1][3]);
                union { uint32_t u[4]; bf16x8 v; } pf;
                {
                    uint32_t x0 = (uint32_t)__shfl((int)pk0a, lane_lo);
                    uint32_t y0 = (uint32_t)__shfl((int)pk1a, lane_lo);
                    pf.u[0] = lowq ? x0 : y0;
                    uint32_t x1 = (uint32_t)__shfl((int)pk0b, lane_lo);
                    uint32_t y1 = (uint32_t)__shfl((int)pk1b, lane_lo);
                    pf.u[1] = lowq ? x1 : y1;
                    uint32_t x2 = (uint32_t)__shfl((int)pk0a, lane_hi);
                    uint32_t y2 = (uint32_t)__shfl((int)pk1a, lane_hi);
                    pf.u[2] = lowq ? x2 : y2;
                    uint32_t x3 = (uint32_t)__shfl((int)pk0b, lane_hi);
                    uint32_t y3 = (uint32_t)__shfl((int)pk1b, lane_hi);
                    pf.u[3] = lowq ? x3 : y3;
                }
#pragma unroll
                for (int nt = 0; nt < 4; ++nt)
                    O[s][nt] = __builtin_amdgcn_mfma_f32_16x16x32_bf16(vf[nt], pf.v, O[s][nt], 0, 0, 0);
            }
        }
    }

#pragma unroll
    for (int s = 0; s < 2; ++s) {
        float l = lsum[s];
        l += __shfl_xor(l, 16);
        l += __shfl_xor(l, 32);
        float inv_l = 1.0f / l;
        int row = b * TT + qbw + s * 16 + c;
#pragma unroll
        for (int nt = 0; nt < 4; ++nt) {
            bf16x4 ov;
#pragma unroll
            for (int r = 0; r < 4; ++r) ov[r] = (bf16_t)(O[s][nt][r] * inv_l);
            *(bf16x4*)(Y + (size_t)row * CC + h * DD + nt * 16 + quad * 4) = ov;
        }
    }
}

// ---------------------------------------------------------------- launch
extern "C" void kernel_launch(void* const* d_in, const int* in_sizes, int n_in,
                              void* d_out, int out_size, void* d_ws, size_t ws_size,
                              hipStream_t stream) {
    const float* x      = (const float*)d_in[0];
    const float* W_attn = (const float*)d_in[1];
    const float* b_attn = (const float*)d_in[2];
    const float* W_proj = (const float*)d_in[3];
    const float* b_proj = (const float*)d_in[4];
    float* out = (float*)d_out;

    unsigned char* ws = (unsigned char*)d_ws;
    size_t off = 0;
    auto alloc = [&](size_t bytes) { void* p = ws + off; off += (bytes + 255) & ~(size_t)255; return p; };
    bf16_t* xb  = (bf16_t*)alloc((size_t)MM * CC * 2);
    bf16_t* WaT = (bf16_t*)alloc((size_t)3 * CC * CC * 2);
    bf16_t* WpT = (bf16_t*)alloc((size_t)CC * CC * 2);
    bf16_t* Qh  = (bf16_t*)alloc((size_t)BH * TT * DD * 2);
    bf16_t* Kh  = (bf16_t*)alloc((size_t)BH * TT * DD * 2);
    bf16_t* Vt  = (bf16_t*)alloc((size_t)BH * TT * DD * 2);
    bf16_t* Yb  = (bf16_t*)alloc((size_t)MM * CC * 2);

    cvt_f32_bf16<<<(MM * CC / 4 + 255) / 256, 256, 0, stream>>>(x, xb, MM * CC / 4);
    transpose_cvt<<<dim3(CC / 32, 3 * CC / 32), dim3(32, 8), 0, stream>>>(W_attn, WaT, CC, 3 * CC);
    transpose_cvt<<<dim3(CC / 32, CC / 32), dim3(32, 8), 0, stream>>>(W_proj, WpT, CC, CC);
    gemm_qkv<<<dim3(MM / 128, 3 * CC / 128), 256, 0, stream>>>(xb, WaT, b_attn, Qh, Kh, Vt);
    flash_attn<<<dim3(768), 256, 0, stream>>>(Qh, Kh, Vt, Yb);
    gemm_proj<<<dim3(MM / 128, CC / 128), 256, 0, stream>>>(Yb, WpT, b_proj, out);
}